// Round 3
// baseline (403.298 us; speedup 1.0000x reference)
//
#include <hip/hip_runtime.h>
#include <stdint.h>

// HashedEmbeddingBag: out[b][d] = sum_{l<50} w[ ((idx[b][l]*A + d*B) % P) % W ]
// B=16384 bags, L=50, E=64 dims, W=1e6 (4MB table, L2-resident).
// Mapping: lane -> dim d (wave64 == EMB_DIM), wave -> bag (readfirstlane'd:
// index loads -> s_load, 64-bit hash -> SALU; VALUBusy measured 6.6%).
//
// R3 changes vs R2 (dur stuck at ~207us, L2-gather bound):
//  1. __builtin_nontemporal_load on the table gathers: skip L1 allocation so
//     each 4B random gather doesn't pay a 64-128B L1 line fill from L2.
//  2. MLP 10 -> 25 loads in flight per wave; __launch_bounds__(256,4) lets
//     VGPR grow to ~128 (trade occupancy 8->4 waves/SIMD for 2.5x per-wave
//     outstanding misses: ~400/CU vs ~230/CU).
//
// Per-lane mod decomposition (per-lane work is ~8 cheap VALU ops):
//   t = mA + hb;  v = t - (t>=P ? P:0);  h = v mod W
//   via  h = (aS + hb_mod [+ (W - P%W) if hb >= P-mA]) folded mod W

#define BAG_LEN 50
#define EMB_DIM 64
#define WEIGHT_SIZE 1000000u
#define HASH_A 9824516537ULL
#define HASH_B 57857966300227ULL
#define HASH_P 117130198221199ULL
#define W_MINUS_PMODW 778801u   // WEIGHT_SIZE - (HASH_P % WEIGHT_SIZE=221199)
#define BATCH 25

__global__ __launch_bounds__(256, 4) void heb_kernel(
    const float* __restrict__ w,
    const int* __restrict__ idx,
    float* __restrict__ out,
    int num_bags)
{
    const int lane = threadIdx.x & 63;
    const int wid  = threadIdx.x >> 6;
    int bag = blockIdx.x * 4 + wid;
    bag = __builtin_amdgcn_readfirstlane(bag);   // wave-uniform by construction
    if (bag >= num_bags) return;

    // per-lane (per-dim) hash offset, computed once
    const uint64_t hb     = ((uint64_t)lane * HASH_B) % HASH_P;
    const uint32_t hb_mod = (uint32_t)(hb % (uint64_t)WEIGHT_SIZE);

    const int* bag_idx = idx + bag * BAG_LEN;    // uniform -> s_load path

    float acc0 = 0.f, acc1 = 0.f;

#pragma unroll
    for (int l0 = 0; l0 < BAG_LEN; l0 += BATCH) {
        uint32_t off[BATCH];
#pragma unroll
        for (int j = 0; j < BATCH; ++j) {
            const uint32_t i  = (uint32_t)bag_idx[l0 + j];               // s_load
            const uint64_t mA = ((uint64_t)i * HASH_A) % HASH_P;         // SALU magic-mod
            const uint32_t aS = (uint32_t)(mA % (uint64_t)WEIGHT_SIZE);  // SALU
            const uint64_t Pm = HASH_P - mA;                             // SALU

            uint32_t r = aS + hb_mod;                    // VALU, sgpr operand
            if (hb >= Pm) r += W_MINUS_PMODW;            // v_cmp_ge_u64 + cndmask+add
            if (r >= 2u * WEIGHT_SIZE) r -= 2u * WEIGHT_SIZE;
            if (r >= WEIGHT_SIZE)      r -= WEIGHT_SIZE;
            off[j] = r;
        }
        float v[BATCH];
#pragma unroll
        for (int j = 0; j < BATCH; ++j)
            v[j] = __builtin_nontemporal_load(&w[off[j]]);  // no L1 alloc/fill
#pragma unroll
        for (int j = 0; j < BATCH; ++j) { if (j & 1) acc1 += v[j]; else acc0 += v[j]; }
    }

    out[bag * EMB_DIM + lane] = acc0 + acc1;             // coalesced
}

extern "C" void kernel_launch(void* const* d_in, const int* in_sizes, int n_in,
                              void* d_out, int out_size, void* d_ws, size_t ws_size,
                              hipStream_t stream) {
    const float* w   = (const float*)d_in[0];   // hashed_weight, 1e6 f32
    const int*   idx = (const int*)d_in[1];     // indices, 16384*50 int32
    float*       out = (float*)d_out;           // 16384*64 f32

    const int num_bags = out_size / EMB_DIM;    // 16384
    const int bags_per_block = 4;               // 256 threads = 4 waves
    const int grid = (num_bags + bags_per_block - 1) / bags_per_block;

    heb_kernel<<<grid, 256, 0, stream>>>(w, idx, out, num_bags);
}

// Round 5
// 213.254 us; speedup vs baseline: 1.8912x; 1.8912x over previous
//
#include <hip/hip_runtime.h>
#include <stdint.h>

// HashedEmbeddingBag: out[b][d] = sum_{l<50} w[ ((idx[b][l]*A + d*B) % P) % W ]
// B=16384 bags, L=50, E=64 dims, W=1e6 (4MB table, per-XCD-L2-resident).
// lane -> dim, wave -> bag (readfirstlane'd: idx loads + 64b hash on SALU).
//
// R5 = R4 with compile fix: __builtin_amdgcn_raw_buffer_load_b32 +
// __builtin_amdgcn_make_buffer_rsrc (ROCm7 clang API).
//
// Within-run A/B, two half-size dispatches (rocprof splits them):
//   V0 (bags lo-half):  plain loads, BATCH=25    -> tests MLP depth 10->25
//   V1 (bags hi-half):  buffer_load aux=SC0 (=1) -> SE scope: bypass L1
//       (no line alloc/fill per 4B gather), still allocates in L2.
//       (R3's NT streamed around L2 -> 400MB HBM -> 2x slower; SC0 differs.)
//
// Per-lane mod decomposition (hash heavy math on SALU, ~8 VALU ops/lane):
//   t = mA + hb;  v = t - (t>=P?P:0);  h = v mod W
//   via h = (aS + hb_mod [+ (W - P%W) if hb >= P-mA]) folded mod W

#define BAG_LEN 50
#define EMB_DIM 64
#define WEIGHT_SIZE 1000000u
#define HASH_A 9824516537ULL
#define HASH_B 57857966300227ULL
#define HASH_P 117130198221199ULL
#define W_MINUS_PMODW 778801u   // WEIGHT_SIZE - (HASH_P % WEIGHT_SIZE=221199)
#define BATCH 25

template<bool BYPASS_L1>
__global__ __launch_bounds__(256, 4) void heb_kernel(
    const float* __restrict__ w,
    const int* __restrict__ idx,
    float* __restrict__ out,
    int bag_lo, int bag_hi)
{
    const int lane = threadIdx.x & 63;
    const int wid  = threadIdx.x >> 6;
    int bag = bag_lo + blockIdx.x * 4 + wid;
    bag = __builtin_amdgcn_readfirstlane(bag);   // wave-uniform by construction
    if (bag >= bag_hi) return;

    // per-lane (per-dim) hash offset, computed once
    const uint64_t hb     = ((uint64_t)lane * HASH_B) % HASH_P;
    const uint32_t hb_mod = (uint32_t)(hb % (uint64_t)WEIGHT_SIZE);

    const int* bag_idx = idx + bag * BAG_LEN;    // uniform -> s_load path

    // buffer resource: base=w, stride=0 (raw), num_records = bytes
    __amdgpu_buffer_rsrc_t rsrc = __builtin_amdgcn_make_buffer_rsrc(
        (void*)w, /*stride*/(short)0, /*num_records*/(int)(WEIGHT_SIZE * 4u),
        /*flags*/0x00020000);

    float acc0 = 0.f, acc1 = 0.f;

#pragma unroll
    for (int l0 = 0; l0 < BAG_LEN; l0 += BATCH) {
        uint32_t off[BATCH];
#pragma unroll
        for (int j = 0; j < BATCH; ++j) {
            const uint32_t i  = (uint32_t)bag_idx[l0 + j];               // s_load
            const uint64_t mA = ((uint64_t)i * HASH_A) % HASH_P;         // SALU magic-mod
            const uint32_t aS = (uint32_t)(mA % (uint64_t)WEIGHT_SIZE);  // SALU
            const uint64_t Pm = HASH_P - mA;                             // SALU

            uint32_t r = aS + hb_mod;                    // VALU, sgpr operand
            if (hb >= Pm) r += W_MINUS_PMODW;            // v_cmp_ge_u64 + cndmask+add
            if (r >= 2u * WEIGHT_SIZE) r -= 2u * WEIGHT_SIZE;
            if (r >= WEIGHT_SIZE)      r -= WEIGHT_SIZE;
            off[j] = r * 4u;                             // byte offset (< 4MB)
        }
        float v[BATCH];
#pragma unroll
        for (int j = 0; j < BATCH; ++j) {
            if (BYPASS_L1) {
                int b = __builtin_amdgcn_raw_buffer_load_b32(
                    rsrc, (int)off[j], /*soffset*/0, /*aux=SC0*/1);
                v[j] = __builtin_bit_cast(float, b);
            } else {
                v[j] = w[off[j] >> 2];
            }
        }
#pragma unroll
        for (int j = 0; j < BATCH; ++j) { if (j & 1) acc1 += v[j]; else acc0 += v[j]; }
    }

    out[bag * EMB_DIM + lane] = acc0 + acc1;             // coalesced
}

extern "C" void kernel_launch(void* const* d_in, const int* in_sizes, int n_in,
                              void* d_out, int out_size, void* d_ws, size_t ws_size,
                              hipStream_t stream) {
    const float* w   = (const float*)d_in[0];   // hashed_weight, 1e6 f32
    const int*   idx = (const int*)d_in[1];     // indices, 16384*50 int32
    float*       out = (float*)d_out;           // 16384*64 f32

    const int num_bags = out_size / EMB_DIM;    // 16384
    const int half     = num_bags / 2;          // 8192
    const int bpb      = 4;                     // 256 threads = 4 waves

    // V0: plain loads on lower half
    heb_kernel<false><<<(half + bpb - 1) / bpb, 256, 0, stream>>>(
        w, idx, out, 0, half);
    // V1: L1-bypass (SC0) loads on upper half
    heb_kernel<true><<<(num_bags - half + bpb - 1) / bpb, 256, 0, stream>>>(
        w, idx, out, half, num_bags);
}